// Round 5
// baseline (302.158 us; speedup 1.0000x reference)
//
#include <hip/hip_runtime.h>

#define CLS 6

constexpr int HIST_BLOCKS  = 2048;
constexpr int HIST_THREADS = 256;
constexpr int WAVES_PB     = HIST_THREADS / 64;
constexpr int NCOPY        = 4;    // replicated LDS histograms
constexpr int CM_STRIDE    = 40;   // 36 buckets padded to 40 words
// staging: per wave, 64 quads; quad j occupies 7 float4 slots (96B data + 16B pad)
// -> read granule = 7*lane + k (7 coprime 32: conflict-free mod the free 2-way alias)

__device__ __forceinline__ int argmax6(float v0, float v1, float v2,
                                       float v3, float v4, float v5) {
    int   pr = 0; float m = v0;
    if (v1 > m) { m = v1; pr = 1; }
    if (v2 > m) { m = v2; pr = 2; }
    if (v3 > m) { m = v3; pr = 3; }
    if (v4 > m) { m = v4; pr = 4; }
    if (v5 > m) { m = v5; pr = 5; }
    return pr;
}

__global__ __launch_bounds__(HIST_THREADS, 5)   // 28KiB stage + cm -> 5 blocks/CU
void cm_hist_kernel(const float* __restrict__ inputs,
                    const int*   __restrict__ targets,
                    const float* __restrict__ wts,
                    unsigned int* __restrict__ cm,
                    long long n_rows) {
    __shared__ float4       stage[WAVES_PB][64 * 7];   // 4 x 7168 B
    __shared__ unsigned int cm_s[NCOPY * CM_STRIDE];

    const int tid  = threadIdx.x;
    const int wave = tid >> 6;
    const int lane = tid & 63;
    if (tid < NCOPY * CM_STRIDE) cm_s[tid] = 0u;
    __syncthreads();

    const float w0 = wts[0], w1 = wts[1], w2 = wts[2];
    const float w3 = wts[3], w4 = wts[4], w5 = wts[5];

    const float4* __restrict__ in4 = (const float4*)inputs;
    const int4*   __restrict__ tg4 = (const int4*)targets;

    const int copy_base = (tid & (NCOPY - 1)) * CM_STRIDE;

    const long long n_quads  = n_rows >> 2;     // 4 rows per quad
    const long long n_chunks = n_quads >> 6;    // 64 quads per wave-chunk

    const long long wave_id = (long long)blockIdx.x * WAVES_PB + wave;
    const long long n_waves = (long long)gridDim.x * WAVES_PB;

    float4* st4 = &stage[wave][0];

    for (long long c = wave_id; c < n_chunks; c += n_waves) {
        const long long base_f4 = c * 384;      // chunk start, float4 units (6144 B)

        // Phase 1: unit-stride global loads (fill-like pattern, ~6.9 TB/s capable)
        float4 r0 = in4[base_f4 +   0 + lane];
        float4 r1 = in4[base_f4 +  64 + lane];
        float4 r2 = in4[base_f4 + 128 + lane];
        float4 r3 = in4[base_f4 + 192 + lane];
        float4 r4 = in4[base_f4 + 256 + lane];
        float4 r5 = in4[base_f4 + 320 + lane];
        int4   t  = tg4[(c << 6) + lane];       // unit-stride already

        // Phase 2: scatter to padded per-quad layout. float4 #u of the chunk
        // belongs to quad u/6, slot u%6 -> granule 7*(u/6) + u%6.
        {
            unsigned u;
            u = 0 * 64 + lane; st4[7 * (u / 6) + (u % 6)] = r0;
            u = 1 * 64 + lane; st4[7 * (u / 6) + (u % 6)] = r1;
            u = 2 * 64 + lane; st4[7 * (u / 6) + (u % 6)] = r2;
            u = 3 * 64 + lane; st4[7 * (u / 6) + (u % 6)] = r3;
            u = 4 * 64 + lane; st4[7 * (u / 6) + (u % 6)] = r4;
            u = 5 * 64 + lane; st4[7 * (u / 6) + (u % 6)] = r5;
        }
        // wave-private buffer: lgkmcnt ordering only, no __syncthreads needed

        // Phase 3: lane reads back its own quad (granules 7*lane .. 7*lane+5)
        float4 f0 = st4[7 * lane + 0];
        float4 f1 = st4[7 * lane + 1];
        float4 f2 = st4[7 * lane + 2];
        float4 f3 = st4[7 * lane + 3];
        float4 f4 = st4[7 * lane + 4];
        float4 f5 = st4[7 * lane + 5];

        int p0 = argmax6(f0.x * w0, f0.y * w1, f0.z * w2, f0.w * w3, f1.x * w4, f1.y * w5);
        int p1 = argmax6(f1.z * w0, f1.w * w1, f2.x * w2, f2.y * w3, f2.z * w4, f2.w * w5);
        int p2 = argmax6(f3.x * w0, f3.y * w1, f3.z * w2, f3.w * w3, f4.x * w4, f4.y * w5);
        int p3 = argmax6(f4.z * w0, f4.w * w1, f5.x * w2, f5.y * w3, f5.z * w4, f5.w * w5);

        atomicAdd(&cm_s[copy_base + p0 * CLS + t.x], 1u);
        atomicAdd(&cm_s[copy_base + p1 * CLS + t.y], 1u);
        atomicAdd(&cm_s[copy_base + p2 * CLS + t.z], 1u);
        atomicAdd(&cm_s[copy_base + p3 * CLS + t.w], 1u);
    }

    // leftover quads (n_quads % 64) via the old strided path; N=8388608 -> none
    for (long long q = (n_chunks << 6) + (long long)blockIdx.x * blockDim.x + tid;
         q < n_quads; q += (long long)gridDim.x * blockDim.x) {
        const long long b = 6 * q;
        float4 f0 = in4[b + 0], f1 = in4[b + 1], f2 = in4[b + 2];
        float4 f3 = in4[b + 3], f4 = in4[b + 4], f5 = in4[b + 5];
        int4   t  = tg4[q];
        int p0 = argmax6(f0.x * w0, f0.y * w1, f0.z * w2, f0.w * w3, f1.x * w4, f1.y * w5);
        int p1 = argmax6(f1.z * w0, f1.w * w1, f2.x * w2, f2.y * w3, f2.z * w4, f2.w * w5);
        int p2 = argmax6(f3.x * w0, f3.y * w1, f3.z * w2, f3.w * w3, f4.x * w4, f4.y * w5);
        int p3 = argmax6(f4.z * w0, f4.w * w1, f5.x * w2, f5.y * w3, f5.z * w4, f5.w * w5);
        atomicAdd(&cm_s[copy_base + p0 * CLS + t.x], 1u);
        atomicAdd(&cm_s[copy_base + p1 * CLS + t.y], 1u);
        atomicAdd(&cm_s[copy_base + p2 * CLS + t.z], 1u);
        atomicAdd(&cm_s[copy_base + p3 * CLS + t.w], 1u);
    }

    // tail rows (n_rows % 4); N=8388608 -> none, kept for generality
    if (blockIdx.x == 0 && tid == 0) {
        for (long long r = (n_quads << 2); r < n_rows; ++r) {
            int pr = argmax6(inputs[r * CLS + 0] * w0, inputs[r * CLS + 1] * w1,
                             inputs[r * CLS + 2] * w2, inputs[r * CLS + 3] * w3,
                             inputs[r * CLS + 4] * w4, inputs[r * CLS + 5] * w5);
            atomicAdd(&cm_s[pr * CLS + targets[r]], 1u);
        }
    }

    __syncthreads();
    if (tid < CLS * CLS) {
        unsigned int v = cm_s[tid]
                       + cm_s[CM_STRIDE + tid]
                       + cm_s[2 * CM_STRIDE + tid]
                       + cm_s[3 * CM_STRIDE + tid];
        if (v) atomicAdd(&cm[tid], v);   // device-scope by default
    }
}

__global__ void macro_score_kernel(const unsigned int* __restrict__ cm,
                                   const float* __restrict__ wts,
                                   float* __restrict__ out) {
    if (threadIdx.x == 0) {
        float c[CLS * CLS];
        #pragma unroll
        for (int i = 0; i < CLS * CLS; ++i) c[i] = (float)cm[i];
        float f1sum = 0.0f;
        #pragma unroll
        for (int i = 0; i < CLS; ++i) {
            float col = 0.0f, row = 0.0f;
            #pragma unroll
            for (int j = 0; j < CLS; ++j) {
                col += c[j * CLS + i];   // cm.sum(axis=0)[i]
                row += c[i * CLS + j];   // cm.sum(axis=1)[i]
            }
            float d  = c[i * CLS + i];
            float pr = d / col;
            float rc = d / row;
            f1sum += 2.0f * pr * rc / (pr + rc);
        }
        out[0] = -(f1sum / (float)CLS);
    }
    if (threadIdx.x < CLS) out[1 + threadIdx.x] = wts[threadIdx.x];
}

extern "C" void kernel_launch(void* const* d_in, const int* in_sizes, int n_in,
                              void* d_out, int out_size, void* d_ws, size_t ws_size,
                              hipStream_t stream) {
    const float* inputs  = (const float*)d_in[0];
    const int*   targets = (const int*)d_in[1];
    const float* wts     = (const float*)d_in[2];
    float*       out     = (float*)d_out;
    unsigned int* cm     = (unsigned int*)d_ws;

    const long long n_rows = (long long)in_sizes[0] / CLS;

    (void)hipMemsetAsync(cm, 0, CLS * CLS * sizeof(unsigned int), stream);
    cm_hist_kernel<<<HIST_BLOCKS, HIST_THREADS, 0, stream>>>(inputs, targets, wts, cm, n_rows);
    macro_score_kernel<<<1, 64, 0, stream>>>(cm, wts, out);
}